// Round 17
// baseline (919.835 us; speedup 1.0000x reference)
//
#include <hip/hip_runtime.h>
#include <cstdint>
#include <cmath>

#define NTOK 197
#define NHEAD 12
#define HD 64
#define CDIM 768
#define KPZ 200
#define VTS 256   // vT row stride (shorts); granule-XOR swizzled

typedef __attribute__((ext_vector_type(8))) short short8v;       // 8 bf16
typedef __attribute__((ext_vector_type(8))) _Float16 half8v;     // 8 fp16
typedef __attribute__((ext_vector_type(4))) float f32x4;

__device__ __forceinline__ unsigned short f2bf(float f) {
  unsigned u = __builtin_bit_cast(unsigned, f);
  unsigned r = (u + 0x7fffu + ((u >> 16) & 1u)) >> 16;   // round-nearest-even
  return (unsigned short)r;
}
__device__ __forceinline__ float bf2f(unsigned short h) {
  unsigned u = ((unsigned)h) << 16;
  return __builtin_bit_cast(float, u);
}

__device__ __forceinline__ void gload_lds16(const unsigned short* g, unsigned short* l) {
  __builtin_amdgcn_global_load_lds(
      (const __attribute__((address_space(1))) unsigned int*)(const void*)g,
      (__attribute__((address_space(3))) unsigned int*)(void*)l, 16, 0, 0);
}

// ---------------------------------------------------------------------------
__global__ __launch_bounds__(256) void bias_pre_kernel(
    const float* __restrict__ table, const int* __restrict__ relidx,
    float* __restrict__ bias_pre, int total)
{
  int i = blockIdx.x * 256 + threadIdx.x;
  if (i >= total) return;
  int nm = i % (NTOK * NTOK);
  int h  = i / (NTOK * NTOK);
  bias_pre[i] = table[relidx[nm] * NHEAD + h];
}

// ---------------------------------------------------------------------------
// Split fp32 [Mreal x C] into 2 scaled-fp16 limb planes [Mpad x C]:
//   t = x*64;  h0 = f16(t);  h1 = f16((t - h0)*4096)
// ---------------------------------------------------------------------------
__global__ __launch_bounds__(256) void split2h_kernel(
    const float* __restrict__ src,
    unsigned short* __restrict__ d0, unsigned short* __restrict__ d1,
    int Mreal, int C, long long total4)
{
  long long idx = (long long)blockIdx.x * 256 + threadIdx.x;
  if (idx >= total4) return;
  long long e = idx * 4;
  int r = (int)(e / C);
  float4 v = make_float4(0.f, 0.f, 0.f, 0.f);
  if (r < Mreal) v = *(const float4*)(src + e);
  const float vv[4] = {v.x, v.y, v.z, v.w};
  ushort4 o0, o1;
  unsigned short* p0 = (unsigned short*)&o0;
  unsigned short* p1 = (unsigned short*)&o1;
#pragma unroll
  for (int i = 0; i < 4; ++i) {
    const float t = vv[i] * 64.0f;
    const _Float16 h0 = (_Float16)t;
    const float rr = t - (float)h0;            // exact (Sterbenz)
    const _Float16 h1 = (_Float16)(rr * 4096.0f);
    p0[i] = __builtin_bit_cast(unsigned short, h0);
    p1[i] = __builtin_bit_cast(unsigned short, h1);
  }
  *(ushort4*)(d0 + e) = o0;
  *(ushort4*)(d1 + e) = o1;
}

// ---------------------------------------------------------------------------
// Scaled-fp16 2-limb MFMA GEMM. 128x64 block tile, BK=32, 4 waves (2x2 of
// 64x32 wave tiles), DOUBLE-buffered 24KB x 2 = 48KB -> 3 blocks/CU,
// __launch_bounds__(256,3) (unified live set ~148 < 170 cap, r16-verified).
// Catalog-minimum T3 schedule, ONE barrier per K-step:
//   stage(buf^1, kt+1)  -- issued FIRST; overwrite-safe: buf^1 was last
//                          read at kt-1, before kt-1's end barrier
//   read 12 frags from buf[cur] (compiler lgkmcnt)
//   24 MFMAs (setprio)  -- covers the stage flight
//   __syncthreads       -- drains vmcnt; buf^1 ready for kt+1
// Per-accumulator MFMA order {00,01,10}, K ascending -- identical to
// r10/r14/r16 (bit-identical output; absmax canary 0.0078125).
// Staging layout = r10's verified BK=32 pattern: granule XOR swizzle on
// pre-swizzled global SOURCE, tid-linear LDS dest, conflict-free reads.
// ---------------------------------------------------------------------------
template <int BANDW>
__global__ __launch_bounds__(256, 3) void gemm_f16(
    const unsigned short* __restrict__ A, size_t aplane,
    const unsigned short* __restrict__ B, size_t bplane,
    const float* __restrict__ bias, float* __restrict__ C,
    int M, int N, int K)
{
  __shared__ unsigned short Asm[2][2][128][32];   // [buf][plane] 16KB/buf
  __shared__ unsigned short Bsm[2][2][64][32];    // [buf][plane]  8KB/buf

  // bijective XCD-chunk block swizzle (m204) + banded decode (64-wide bn)
  const int nwg = gridDim.x;
  const int orig = blockIdx.x;
  const int q = nwg >> 3, r = nwg & 7;
  const int xcd = orig & 7, pos = orig >> 3;
  const int wg = (xcd < r ? xcd * (q + 1) : r * (q + 1) + (xcd - r) * q) + pos;
  const int byCount = (M + 127) >> 7;
  const int bandSz = byCount * BANDW;
  const int band = wg / bandSz;
  const int rem = wg % bandSz;
  const int by = rem / BANDW;
  const int bx = band * BANDW + rem % BANDW;
  const int bm = by * 128, bn = bx * 64;

  const int tid = threadIdx.x;
  const int w = tid >> 6, lane = tid & 63;
  const int wr = w >> 1, wc = w & 1;               // 2x2 wave grid
  const int sr = tid >> 2, gi = tid & 3;           // staging row / granule
  const int sgW = (gi ^ ((sr >> 1) & 3)) * 8;      // swizzled SOURCE col
  const int scW = gi * 8;                          // linear LDS dest col
  const int fr = lane & 15;
  const int fq = lane >> 4;
  const int mrow = wr * 64 + fr;
  const int ncol = wc * 32;
  const int kcsw = 8 * (fq ^ ((fr >> 1) & 3));     // swizzled read col

  const size_t aoff0 = (size_t)(bm + sr) * K + sgW;
  const size_t aoff1 = (size_t)(bm + sr + 64) * K + sgW;
  const size_t boff  = (size_t)(bn + sr) * K + sgW;   // sr 0..63 covers B tile

  f32x4 accA[4][2], accB[4][2];
#pragma unroll
  for (int i = 0; i < 4; ++i)
#pragma unroll
    for (int j = 0; j < 2; ++j) {
      accA[i][j] = (f32x4){0.f, 0.f, 0.f, 0.f};
      accB[i][j] = (f32x4){0.f, 0.f, 0.f, 0.f};
    }

  auto stage = [&](int buf, int k0) {
#pragma unroll
    for (int p = 0; p < 2; ++p) {
      const unsigned short* Ap = A + (size_t)p * aplane + k0;
      gload_lds16(Ap + aoff0, &Asm[buf][p][sr][scW]);
      gload_lds16(Ap + aoff1, &Asm[buf][p][sr + 64][scW]);
      gload_lds16(B + (size_t)p * bplane + k0 + boff, &Bsm[buf][p][sr & 63][scW]);
    }
  };

  const int NT = K >> 5;     // 24 K-steps

  stage(0, 0);
  __syncthreads();

#pragma unroll 1
  for (int kt = 0; kt < NT; ++kt) {
    const int cur = kt & 1;
    // 1) prefetch next tile into the other buffer (flight covered below)
    if (kt + 1 < NT) stage(cur ^ 1, (kt + 1) * 32);
    __builtin_amdgcn_sched_barrier(0);
    // 2) read all 12 fragments of tile kt
    half8v a0[4], a1[4], b0[2], b1[2];
#pragma unroll
    for (int mt = 0; mt < 4; ++mt) {
      a0[mt] = *(const half8v*)&Asm[cur][0][mrow + mt * 16][kcsw];
      a1[mt] = *(const half8v*)&Asm[cur][1][mrow + mt * 16][kcsw];
    }
#pragma unroll
    for (int nt = 0; nt < 2; ++nt) {
      b0[nt] = *(const half8v*)&Bsm[cur][0][ncol + nt * 16 + fr][kcsw];
      b1[nt] = *(const half8v*)&Bsm[cur][1][ncol + nt * 16 + fr][kcsw];
    }
    // 3) 24 MFMAs (order {00,01,10}, identical to prior rounds)
    __builtin_amdgcn_s_setprio(1);
#pragma unroll
    for (int mt = 0; mt < 4; ++mt)
#pragma unroll
      for (int nt = 0; nt < 2; ++nt)
        accA[mt][nt] = __builtin_amdgcn_mfma_f32_16x16x32_f16(
            a0[mt], b0[nt], accA[mt][nt], 0, 0, 0);
#pragma unroll
    for (int mt = 0; mt < 4; ++mt)
#pragma unroll
      for (int nt = 0; nt < 2; ++nt)
        accB[mt][nt] = __builtin_amdgcn_mfma_f32_16x16x32_f16(
            a0[mt], b1[nt], accB[mt][nt], 0, 0, 0);
#pragma unroll
    for (int mt = 0; mt < 4; ++mt)
#pragma unroll
      for (int nt = 0; nt < 2; ++nt)
        accB[mt][nt] = __builtin_amdgcn_mfma_f32_16x16x32_f16(
            a1[mt], b0[nt], accB[mt][nt], 0, 0, 0);
    __builtin_amdgcn_s_setprio(0);
    // 4) one barrier: drains prefetch (vmcnt) + read-complete for overwrite
    __syncthreads();
  }

  // epilogue: C/D layout col = lane&15, row = (lane>>4)*4 + j
  constexpr float S1 = 1.0f / 4096.0f;
#pragma unroll
  for (int nt = 0; nt < 2; ++nt) {
    const int col = bn + wc * 32 + nt * 16 + fr;
    const float bcol = bias ? bias[col] : 0.0f;
#pragma unroll
    for (int mt = 0; mt < 4; ++mt) {
      const int rowbase = bm + wr * 64 + mt * 16 + fq * 4;
#pragma unroll
      for (int j = 0; j < 4; ++j) {
        const int row = rowbase + j;
        if (row < M)
          C[(size_t)row * N + col] =
              (accA[mt][nt][j] + accB[mt][nt][j] * S1) * S1 + bcol;
      }
    }
  }
}

// ---------------------------------------------------------------------------
// Fused binary attention per (b,h), 8 waves, MFMA PV (unchanged from r15).
// ---------------------------------------------------------------------------
__global__ __launch_bounds__(512, 4) void attn_kernel(
    const float* __restrict__ qkv, const float* __restrict__ bias_pre,
    unsigned short* __restrict__ att0, unsigned short* __restrict__ att1)
{
  __shared__ unsigned short vT[2][HD][VTS];
  __shared__ unsigned char  zb[32][KPZ];
  __shared__ unsigned long long qb[200];
  __shared__ unsigned long long kbt[200];
  __shared__ float red[16];

  const int bh = blockIdx.x;
  const int b = bh / NHEAD;
  const int h = bh % NHEAD;
  const int tid = threadIdx.x;
  const int w = tid >> 6;
  const int lane = tid & 63;
  const float* base = qkv + (size_t)b * (NTOK * 3 * CDIM) + h * HD;

  float sq = 0.f, sk = 0.f;
  for (int n = w; n < NTOK; n += 8) {
    const float* row = base + (size_t)n * (3 * CDIM);
    const float qv = row[lane];
    const float kv = row[CDIM + lane];
    const float vv = row[2 * CDIM + lane];
    sq += fabsf(qv);
    sk += fabsf(kv);
    const unsigned long long qm = __ballot(qv >= 0.0f);
    const unsigned long long km = __ballot(kv >= 0.0f);
    if (lane == 0) { qb[n] = qm; kbt[n] = km; }
    const float c = fminf(fmaxf(vv, -2.0f), 2.0f);
    float a = fabsf(c);
#pragma unroll
    for (int off = 32; off; off >>= 1) a = fmaxf(a, __shfl_xor(a, off));
    const float s = 127.0f / (a + 1e-8f);
    const float vq = rintf(c * s) / s;
    const unsigned short l0 = f2bf(vq);
    const unsigned short l1 = f2bf(vq - bf2f(l0));
    const int gsw = ((((n >> 3) ^ (lane & 31)) << 3) | (n & 7));
    vT[0][lane][gsw] = l0;
    vT[1][lane][gsw] = l1;
  }
#pragma unroll
  for (int off = 32; off; off >>= 1) {
    sq += __shfl_xor(sq, off);
    sk += __shfl_xor(sk, off);
  }
  if (lane == 0) { red[w] = sq; red[8 + w] = sk; }
  __syncthreads();
  float s_q = 0.f, s_k = 0.f;
#pragma unroll
  for (int i = 0; i < 8; ++i) { s_q += red[i]; s_k += red[8 + i]; }
  s_q *= (1.0f / (NTOK * HD));
  s_k *= (1.0f / (NTOK * HD));
  const float coef = s_q * s_k * 0.125f;

  const float* biash = bias_pre + (size_t)h * (NTOK * NTOK);
  const float SP = 1.0f / 255.0f;

  const int mt = w >> 2;
  const int nt = w & 3;
  const int arow = mt * 16 + (lane & 15);
  const int bcol = nt * 16 + (lane & 15);
  const int kq8 = 8 * (lane >> 4);
  const int rowb = mt * 16 + ((lane >> 4) << 2);
  const int colOut = h * HD + bcol;
  const int bsw = bcol & 31;   // vT read swizzle key

  for (int g = 0; g < 7; ++g) {
    const int r0 = g * 32;

#pragma unroll
    for (int i = 0; i < 4; ++i) {
      const int r = r0 + w * 4 + i;
      if (r < NTOK) {
        const unsigned long long qn = qb[r];
        const float* brow = biash + (size_t)r * NTOK;
        float lg[4];
#pragma unroll
        for (int t = 0; t < 4; ++t) {
          const int m = lane + t * 64;
          if (m < NTOK) {
            const int dot = 64 - 2 * __popcll(qn ^ kbt[m]);
            lg[t] = fmaf(coef, (float)dot, brow[m]);
          } else {
            lg[t] = -INFINITY;
          }
        }
        float mx = fmaxf(fmaxf(lg[0], lg[1]), fmaxf(lg[2], lg[3]));
#pragma unroll
        for (int off = 32; off; off >>= 1) mx = fmaxf(mx, __shfl_xor(mx, off));
        const float p0 = expf(lg[0] - mx);
        const float p1 = expf(lg[1] - mx);
        const float p2 = expf(lg[2] - mx);
        const float p3 = expf(lg[3] - mx);
        float sum = p0 + p1 + p2 + p3;
#pragma unroll
        for (int off = 32; off; off >>= 1) sum += __shfl_xor(sum, off);
        float z0 = rintf((p0 / sum) / SP); z0 = fminf(fmaxf(z0, 0.f), 255.f);
        float z1 = rintf((p1 / sum) / SP); z1 = fminf(fmaxf(z1, 0.f), 255.f);
        float z2 = rintf((p2 / sum) / SP); z2 = fminf(fmaxf(z2, 0.f), 255.f);
        float z3 = rintf((p3 / sum) / SP); z3 = fminf(fmaxf(z3, 0.f), 255.f);
        const int zr = w * 4 + i;
        zb[zr][lane]       = (unsigned char)(int)z0;
        zb[zr][lane + 64]  = (unsigned char)(int)z1;
        zb[zr][lane + 128] = (unsigned char)(int)z2;
        if (lane + 192 < NTOK) zb[zr][lane + 192] = (unsigned char)(int)z3;
      }
    }
    __syncthreads();

    f32x4 acc = (f32x4){0.f, 0.f, 0.f, 0.f};
#pragma unroll
    for (int k0 = 0; k0 < 192; k0 += 32) {
      const unsigned long long a8 =
          *(const unsigned long long*)&zb[arow][k0 + kq8];
      short8v af;
#pragma unroll
      for (int j = 0; j < 8; ++j) {
        const float f = (float)((unsigned)(a8 >> (8 * j)) & 0xFFu);
        af[j] = (short)(__builtin_bit_cast(unsigned, f) >> 16);
      }
      const int kg = (((k0 + kq8) >> 3) ^ bsw) << 3;
      const short8v b0 = *(const short8v*)&vT[0][bcol][kg];
      const short8v b1 = *(const short8v*)&vT[1][bcol][kg];
      acc = __builtin_amdgcn_mfma_f32_16x16x32_bf16(af, b0, acc, 0, 0, 0);
      acc = __builtin_amdgcn_mfma_f32_16x16x32_bf16(af, b1, acc, 0, 0, 0);
    }
#pragma unroll
    for (int j = 0; j < 4; ++j) {
      float a = acc[j];
#pragma unroll
      for (int m = 192; m < 197; ++m) {
        const int mg = ((((m >> 3) ^ bsw) << 3) | (m & 7));
        const float zv = (float)zb[rowb + j][m];
        const float vv = bf2f(vT[0][bcol][mg]) + bf2f(vT[1][bcol][mg]);
        a = fmaf(zv, vv, a);
      }
      acc[j] = a;
    }
#pragma unroll
    for (int j = 0; j < 4; ++j) {
      const int row = r0 + rowb + j;
      if (row < NTOK) {
        const size_t off = ((size_t)b * NTOK + row) * CDIM + colOut;
        const float t = acc[j] * SP * 64.0f;     // prescaled x64
        const _Float16 h0 = (_Float16)t;
        const float rr = t - (float)h0;
        const _Float16 h1 = (_Float16)(rr * 4096.0f);
        att0[off] = __builtin_bit_cast(unsigned short, h0);
        att1[off] = __builtin_bit_cast(unsigned short, h1);
      }
    }
    __syncthreads();
  }
}

// ---------------------------------------------------------------------------
extern "C" void kernel_launch(void* const* d_in, const int* in_sizes, int n_in,
                              void* d_out, int out_size, void* d_ws, size_t ws_size,
                              hipStream_t stream)
{
  (void)in_sizes; (void)n_in; (void)out_size;
  const float* x      = (const float*)d_in[0];
  const float* qkv_w  = (const float*)d_in[1];
  const float* proj_w = (const float*)d_in[2];
  const float* proj_b = (const float*)d_in[3];
  const float* table  = (const float*)d_in[4];
  const int*   relidx = (const int*)d_in[5];
  float* out = (float*)d_out;

  const size_t biasElems = (size_t)NHEAD * NTOK * NTOK;
  const size_t wqPlane = (size_t)(3 * CDIM) * CDIM;
  const size_t wpPlane = (size_t)CDIM * CDIM;

  // adaptive batch chunk (128-aligned Mpad); 2 limb planes
  int nb = 128;
  size_t Mpad = 0;
  for (;; nb >>= 1) {
    size_t Mreal = (size_t)nb * NTOK;
    Mpad = (Mreal + 127) & ~(size_t)127;
    size_t need = biasElems * 4 + (2 * wqPlane + 2 * wpPlane) * 2 +
                  2 * Mpad * CDIM * 2 +           // x/att split planes (f16)
                  Mreal * (size_t)(3 * CDIM) * 4; // qkv buf (f32)
    if (need <= ws_size || nb == 1) break;
  }

  char* p = (char*)d_ws;
  float* bias_pre = (float*)p;               p += biasElems * 4;
  unsigned short* wq = (unsigned short*)p;   p += 2 * wqPlane * 2;
  unsigned short* wp = (unsigned short*)p;   p += 2 * wpPlane * 2;
  unsigned short* xs = (unsigned short*)p;   p += 2 * Mpad * CDIM * 2;
  float* qkvbuf = (float*)p;

  const size_t xPlane = Mpad * CDIM;

  {
    const int total = (int)biasElems;
    bias_pre_kernel<<<(total + 255) / 256, 256, 0, stream>>>(table, relidx, bias_pre, total);
  }
  {
    long long t4 = (long long)(3 * CDIM) * CDIM / 4;
    split2h_kernel<<<(int)((t4 + 255) / 256), 256, 0, stream>>>(
        qkv_w, wq, wq + wqPlane, 3 * CDIM, CDIM, t4);
    t4 = (long long)CDIM * CDIM / 4;
    split2h_kernel<<<(int)((t4 + 255) / 256), 256, 0, stream>>>(
        proj_w, wp, wp + wpPlane, CDIM, CDIM, t4);
  }

  for (int b0 = 0; b0 < 128; b0 += nb) {
    const int curB = (128 - b0 < nb) ? (128 - b0) : nb;
    const int Mreal = curB * NTOK;
    {
      long long t4 = (long long)Mpad * CDIM / 4;
      split2h_kernel<<<(int)((t4 + 255) / 256), 256, 0, stream>>>(
          x + (size_t)b0 * NTOK * CDIM, xs, xs + xPlane, Mreal, CDIM, t4);
    }
    const int mtiles = (int)(Mpad / 128);
    // qkv: 36 N-tiles of 64, BANDW=18 -> 2 bands
    gemm_f16<18><<<mtiles * 36, 256, 0, stream>>>(
        xs, xPlane, wq, wqPlane, nullptr, qkvbuf, Mreal, 3 * CDIM, CDIM);
    attn_kernel<<<curB * NHEAD, 512, 0, stream>>>(qkvbuf, bias_pre, xs, xs + xPlane);
    // proj: 12 N-tiles of 64, BANDW=12 -> single band
    gemm_f16<12><<<mtiles * 12, 256, 0, stream>>>(
        xs, xPlane, wp, wpPlane, proj_b, out + (size_t)b0 * NTOK * CDIM,
        Mreal, CDIM, CDIM);
  }
}

// Round 18
// 799.326 us; speedup vs baseline: 1.1508x; 1.1508x over previous
//
#include <hip/hip_runtime.h>
#include <cstdint>
#include <cmath>

#define NTOK 197
#define NHEAD 12
#define HD 64
#define CDIM 768
#define KPZ 200   // zb row stride (bf16 shorts)
#define KPV 200   // vT row stride (shorts)

typedef __attribute__((ext_vector_type(8))) short short8v;       // 8 bf16
typedef __attribute__((ext_vector_type(8))) _Float16 half8v;     // 8 fp16
typedef __attribute__((ext_vector_type(4))) float f32x4;

__device__ __forceinline__ unsigned short f2bf(float f) {
  unsigned u = __builtin_bit_cast(unsigned, f);
  unsigned r = (u + 0x7fffu + ((u >> 16) & 1u)) >> 16;   // round-nearest-even
  return (unsigned short)r;
}
__device__ __forceinline__ float bf2f(unsigned short h) {
  unsigned u = ((unsigned)h) << 16;
  return __builtin_bit_cast(float, u);
}

__device__ __forceinline__ void gload_lds16(const unsigned short* g, unsigned short* l) {
  __builtin_amdgcn_global_load_lds(
      (const __attribute__((address_space(1))) unsigned int*)(const void*)g,
      (__attribute__((address_space(3))) unsigned int*)(void*)l, 16, 0, 0);
}

// ---------------------------------------------------------------------------
__global__ __launch_bounds__(256) void bias_pre_kernel(
    const float* __restrict__ table, const int* __restrict__ relidx,
    float* __restrict__ bias_pre, int total)
{
  int i = blockIdx.x * 256 + threadIdx.x;
  if (i >= total) return;
  int nm = i % (NTOK * NTOK);
  int h  = i / (NTOK * NTOK);
  bias_pre[i] = table[relidx[nm] * NHEAD + h];
}

// ---------------------------------------------------------------------------
// Split fp32 [Mreal x C] into 2 scaled-fp16 limb planes [Mpad x C]:
//   t = x*64;  h0 = f16(t);  h1 = f16((t - h0)*4096)
// ---------------------------------------------------------------------------
__global__ __launch_bounds__(256) void split2h_kernel(
    const float* __restrict__ src,
    unsigned short* __restrict__ d0, unsigned short* __restrict__ d1,
    int Mreal, int C, long long total4)
{
  long long idx = (long long)blockIdx.x * 256 + threadIdx.x;
  if (idx >= total4) return;
  long long e = idx * 4;
  int r = (int)(e / C);
  float4 v = make_float4(0.f, 0.f, 0.f, 0.f);
  if (r < Mreal) v = *(const float4*)(src + e);
  const float vv[4] = {v.x, v.y, v.z, v.w};
  ushort4 o0, o1;
  unsigned short* p0 = (unsigned short*)&o0;
  unsigned short* p1 = (unsigned short*)&o1;
#pragma unroll
  for (int i = 0; i < 4; ++i) {
    const float t = vv[i] * 64.0f;
    const _Float16 h0 = (_Float16)t;
    const float rr = t - (float)h0;            // exact (Sterbenz)
    const _Float16 h1 = (_Float16)(rr * 4096.0f);
    p0[i] = __builtin_bit_cast(unsigned short, h0);
    p1[i] = __builtin_bit_cast(unsigned short, h1);
  }
  *(ushort4*)(d0 + e) = o0;
  *(ushort4*)(d1 + e) = o1;
}

// ---------------------------------------------------------------------------
// Scaled-fp16 2-limb MFMA GEMM -- EXACT r16 champion config (777us).
// 128x64 block tile, BK=64, 4 waves (2x2 of 64x32), __launch_bounds__(256,3),
// 3 blocks/CU (unified live set ~148 < 170 cap, no spill). Two-phase K-tile:
// phase0 streams K-half-0 frags; phase1 reads all K-half-1 frags -> barrier
// -> stage(next) -> MFMAs (cover flight) -> barrier. Granule XOR swizzle
// g^(row&7) on pre-swizzled global source, tid-linear LDS dest.
// Per-element MFMA order {00,01,10} per K-32 slice, K ascending --
// bit-identical output (absmax canary 0.0078125).
// ---------------------------------------------------------------------------
template <int BANDW>
__global__ __launch_bounds__(256, 3) void gemm_f16(
    const unsigned short* __restrict__ A, size_t aplane,
    const unsigned short* __restrict__ B, size_t bplane,
    const float* __restrict__ bias, float* __restrict__ C,
    int M, int N, int K)
{
  __shared__ unsigned short Asm[2][128][64];   // 32KB
  __shared__ unsigned short Bsm[2][64][64];    // 16KB

  const int nwg = gridDim.x;
  const int orig = blockIdx.x;
  const int q = nwg >> 3, r = nwg & 7;
  const int xcd = orig & 7, pos = orig >> 3;
  const int wg = (xcd < r ? xcd * (q + 1) : r * (q + 1) + (xcd - r) * q) + pos;
  const int byCount = (M + 127) >> 7;
  const int bandSz = byCount * BANDW;
  const int band = wg / bandSz;
  const int rem = wg % bandSz;
  const int by = rem / BANDW;
  const int bx = band * BANDW + rem % BANDW;
  const int bm = by * 128, bn = bx * 64;

  const int tid = threadIdx.x;
  const int w = tid >> 6, lane = tid & 63;
  const int wr = w >> 1, wc = w & 1;
  const int srow = tid >> 3;
  const int sslot = tid & 7;
  const int sgW = (sslot ^ (srow & 7)) * 8;
  const int fr = lane & 15;
  const int fq = lane >> 4;
  const int mrow = wr * 64 + fr;
  const int ncol = wc * 32;
  const int kc0 = 8 * ((fq) ^ (fr & 7));
  const int kc1 = 8 * ((4 + fq) ^ (fr & 7));

  size_t aoffs[4], boffs[2];
#pragma unroll
  for (int ps = 0; ps < 4; ++ps) aoffs[ps] = (size_t)(bm + srow + 32 * ps) * K + sgW;
#pragma unroll
  for (int ps = 0; ps < 2; ++ps) boffs[ps] = (size_t)(bn + srow + 32 * ps) * K + sgW;

  f32x4 accA[4][2], accB[4][2];
#pragma unroll
  for (int i = 0; i < 4; ++i)
#pragma unroll
    for (int j = 0; j < 2; ++j) {
      accA[i][j] = (f32x4){0.f, 0.f, 0.f, 0.f};
      accB[i][j] = (f32x4){0.f, 0.f, 0.f, 0.f};
    }

  auto stage = [&](int k0) {
#pragma unroll
    for (int ps = 0; ps < 4; ++ps) {
      const int dr = srow + 32 * ps;
      gload_lds16(A + aoffs[ps] + k0,          &Asm[0][dr][sslot * 8]);
      gload_lds16(A + aplane + aoffs[ps] + k0, &Asm[1][dr][sslot * 8]);
    }
#pragma unroll
    for (int ps = 0; ps < 2; ++ps) {
      const int dr = srow + 32 * ps;
      gload_lds16(B + boffs[ps] + k0,          &Bsm[0][dr][sslot * 8]);
      gload_lds16(B + bplane + boffs[ps] + k0, &Bsm[1][dr][sslot * 8]);
    }
  };

  stage(0);
  __syncthreads();

#pragma unroll 1
  for (int k0 = 0; k0 < K; k0 += 64) {
    // ---- phase 0: K-half 0 (stream A per mt; B cached) ----
    {
      half8v b0[2], b1[2];
#pragma unroll
      for (int nt = 0; nt < 2; ++nt) {
        b0[nt] = *(const half8v*)&Bsm[0][ncol + nt * 16 + fr][kc0];
        b1[nt] = *(const half8v*)&Bsm[1][ncol + nt * 16 + fr][kc0];
      }
#pragma unroll
      for (int mt = 0; mt < 4; ++mt) {
        const half8v a0 = *(const half8v*)&Asm[0][mrow + mt * 16][kc0];
        const half8v a1 = *(const half8v*)&Asm[1][mrow + mt * 16][kc0];
#pragma unroll
        for (int nt = 0; nt < 2; ++nt)
          accA[mt][nt] = __builtin_amdgcn_mfma_f32_16x16x32_f16(
              a0, b0[nt], accA[mt][nt], 0, 0, 0);
#pragma unroll
        for (int nt = 0; nt < 2; ++nt)
          accB[mt][nt] = __builtin_amdgcn_mfma_f32_16x16x32_f16(
              a0, b1[nt], accB[mt][nt], 0, 0, 0);
#pragma unroll
        for (int nt = 0; nt < 2; ++nt)
          accB[mt][nt] = __builtin_amdgcn_mfma_f32_16x16x32_f16(
              a1, b0[nt], accB[mt][nt], 0, 0, 0);
      }
    }
    // ---- phase 1: read ALL K-half-1 frags -> barrier -> stage -> MFMAs ----
    {
      half8v a0[4], a1[4], b0[2], b1[2];
#pragma unroll
      for (int mt = 0; mt < 4; ++mt) {
        a0[mt] = *(const half8v*)&Asm[0][mrow + mt * 16][kc1];
        a1[mt] = *(const half8v*)&Asm[1][mrow + mt * 16][kc1];
      }
#pragma unroll
      for (int nt = 0; nt < 2; ++nt) {
        b0[nt] = *(const half8v*)&Bsm[0][ncol + nt * 16 + fr][kc1];
        b1[nt] = *(const half8v*)&Bsm[1][ncol + nt * 16 + fr][kc1];
      }
      __syncthreads();                 // all reads of this buffer complete
      if (k0 + 64 < K) stage(k0 + 64);
      __builtin_amdgcn_sched_barrier(0);
#pragma unroll
      for (int mt = 0; mt < 4; ++mt)
#pragma unroll
        for (int nt = 0; nt < 2; ++nt)
          accA[mt][nt] = __builtin_amdgcn_mfma_f32_16x16x32_f16(
              a0[mt], b0[nt], accA[mt][nt], 0, 0, 0);
#pragma unroll
      for (int mt = 0; mt < 4; ++mt)
#pragma unroll
        for (int nt = 0; nt < 2; ++nt)
          accB[mt][nt] = __builtin_amdgcn_mfma_f32_16x16x32_f16(
              a0[mt], b1[nt], accB[mt][nt], 0, 0, 0);
#pragma unroll
      for (int mt = 0; mt < 4; ++mt)
#pragma unroll
        for (int nt = 0; nt < 2; ++nt)
          accB[mt][nt] = __builtin_amdgcn_mfma_f32_16x16x32_f16(
              a1[mt], b0[nt], accB[mt][nt], 0, 0, 0);
    }
    __syncthreads();                   // staged loads drained; next tile visible
  }

  // epilogue: C/D layout col = lane&15, row = (lane>>4)*4 + j
  constexpr float S1 = 1.0f / 4096.0f;
#pragma unroll
  for (int nt = 0; nt < 2; ++nt) {
    const int col = bn + wc * 32 + nt * 16 + fr;
    const float bcol = bias ? bias[col] : 0.0f;
#pragma unroll
    for (int mt = 0; mt < 4; ++mt) {
      const int rowbase = bm + wr * 64 + mt * 16 + fq * 4;
#pragma unroll
      for (int j = 0; j < 4; ++j) {
        const int row = rowbase + j;
        if (row < M)
          C[(size_t)row * N + col] =
              (accA[mt][nt][j] + accB[mt][nt][j] * S1) * S1 + bcol;
      }
    }
  }
}

// ---------------------------------------------------------------------------
// Fused binary attention per (b,h), 8 waves, MFMA PV.
// Change vs r16: zb stored as BF16 (z in [0,255] is bf16-exact, f2bf of an
// integer is exact) -> the PV A-fragment is a direct short8v LDS read; the
// entire per-k0 u8->bf16 unpack (~240 VALU/wave/group) is removed. MFMA
// inputs bit-identical -> output bit-identical. vT back to plain 200-stride
// (r15 swizzle measured neutral). LDS total 67.3KB -> 2 blocks/CU.
// ---------------------------------------------------------------------------
__global__ __launch_bounds__(512, 4) void attn_kernel(
    const float* __restrict__ qkv, const float* __restrict__ bias_pre,
    unsigned short* __restrict__ att0, unsigned short* __restrict__ att1)
{
  __shared__ unsigned short vT[2][HD][KPV];       // 51,200 B
  __shared__ unsigned short zb16[32][KPZ];        // 12,800 B (bf16 z)
  __shared__ unsigned long long qb[200];          //  1,600 B
  __shared__ unsigned long long kbt[200];         //  1,600 B
  __shared__ float red[16];                       //     64 B (total 67,264)

  const int bh = blockIdx.x;
  const int b = bh / NHEAD;
  const int h = bh % NHEAD;
  const int tid = threadIdx.x;
  const int w = tid >> 6;
  const int lane = tid & 63;
  const float* base = qkv + (size_t)b * (NTOK * 3 * CDIM) + h * HD;

  float sq = 0.f, sk = 0.f;
  for (int n = w; n < NTOK; n += 8) {
    const float* row = base + (size_t)n * (3 * CDIM);
    const float qv = row[lane];
    const float kv = row[CDIM + lane];
    const float vv = row[2 * CDIM + lane];
    sq += fabsf(qv);
    sk += fabsf(kv);
    const unsigned long long qm = __ballot(qv >= 0.0f);
    const unsigned long long km = __ballot(kv >= 0.0f);
    if (lane == 0) { qb[n] = qm; kbt[n] = km; }
    const float c = fminf(fmaxf(vv, -2.0f), 2.0f);
    float a = fabsf(c);
#pragma unroll
    for (int off = 32; off; off >>= 1) a = fmaxf(a, __shfl_xor(a, off));
    const float s = 127.0f / (a + 1e-8f);
    const float vq = rintf(c * s) / s;
    const unsigned short l0 = f2bf(vq);
    const unsigned short l1 = f2bf(vq - bf2f(l0));
    vT[0][lane][n] = l0;
    vT[1][lane][n] = l1;
  }
#pragma unroll
  for (int off = 32; off; off >>= 1) {
    sq += __shfl_xor(sq, off);
    sk += __shfl_xor(sk, off);
  }
  if (lane == 0) { red[w] = sq; red[8 + w] = sk; }
  __syncthreads();
  float s_q = 0.f, s_k = 0.f;
#pragma unroll
  for (int i = 0; i < 8; ++i) { s_q += red[i]; s_k += red[8 + i]; }
  s_q *= (1.0f / (NTOK * HD));
  s_k *= (1.0f / (NTOK * HD));
  const float coef = s_q * s_k * 0.125f;

  const float* biash = bias_pre + (size_t)h * (NTOK * NTOK);
  const float SP = 1.0f / 255.0f;

  const int mt = w >> 2;
  const int nt = w & 3;
  const int arow = mt * 16 + (lane & 15);
  const int bcol = nt * 16 + (lane & 15);
  const int kq8 = 8 * (lane >> 4);
  const int rowb = mt * 16 + ((lane >> 4) << 2);
  const int colOut = h * HD + bcol;

  for (int g = 0; g < 7; ++g) {
    const int r0 = g * 32;

#pragma unroll
    for (int i = 0; i < 4; ++i) {
      const int r = r0 + w * 4 + i;
      if (r < NTOK) {
        const unsigned long long qn = qb[r];
        const float* brow = biash + (size_t)r * NTOK;
        float lg[4];
#pragma unroll
        for (int t = 0; t < 4; ++t) {
          const int m = lane + t * 64;
          if (m < NTOK) {
            const int dot = 64 - 2 * __popcll(qn ^ kbt[m]);
            lg[t] = fmaf(coef, (float)dot, brow[m]);
          } else {
            lg[t] = -INFINITY;
          }
        }
        float mx = fmaxf(fmaxf(lg[0], lg[1]), fmaxf(lg[2], lg[3]));
#pragma unroll
        for (int off = 32; off; off >>= 1) mx = fmaxf(mx, __shfl_xor(mx, off));
        const float p0 = expf(lg[0] - mx);
        const float p1 = expf(lg[1] - mx);
        const float p2 = expf(lg[2] - mx);
        const float p3 = expf(lg[3] - mx);
        float sum = p0 + p1 + p2 + p3;
#pragma unroll
        for (int off = 32; off; off >>= 1) sum += __shfl_xor(sum, off);
        float z0 = rintf((p0 / sum) / SP); z0 = fminf(fmaxf(z0, 0.f), 255.f);
        float z1 = rintf((p1 / sum) / SP); z1 = fminf(fmaxf(z1, 0.f), 255.f);
        float z2 = rintf((p2 / sum) / SP); z2 = fminf(fmaxf(z2, 0.f), 255.f);
        float z3 = rintf((p3 / sum) / SP); z3 = fminf(fmaxf(z3, 0.f), 255.f);
        const int zr = w * 4 + i;
        zb16[zr][lane]       = f2bf(z0);   // exact: z integer <= 255
        zb16[zr][lane + 64]  = f2bf(z1);
        zb16[zr][lane + 128] = f2bf(z2);
        if (lane + 192 < NTOK) zb16[zr][lane + 192] = f2bf(z3);
      }
    }
    __syncthreads();

    f32x4 acc = (f32x4){0.f, 0.f, 0.f, 0.f};
#pragma unroll
    for (int k0 = 0; k0 < 192; k0 += 32) {
      const short8v af = *(const short8v*)&zb16[arow][k0 + kq8];
      const short8v b0 = *(const short8v*)&vT[0][bcol][k0 + kq8];
      const short8v b1 = *(const short8v*)&vT[1][bcol][k0 + kq8];
      acc = __builtin_amdgcn_mfma_f32_16x16x32_bf16(af, b0, acc, 0, 0, 0);
      acc = __builtin_amdgcn_mfma_f32_16x16x32_bf16(af, b1, acc, 0, 0, 0);
    }
#pragma unroll
    for (int j = 0; j < 4; ++j) {
      float a = acc[j];
#pragma unroll
      for (int m = 192; m < 197; ++m) {
        const float zv = bf2f(zb16[rowb + j][m]);
        const float vv = bf2f(vT[0][bcol][m]) + bf2f(vT[1][bcol][m]);
        a = fmaf(zv, vv, a);
      }
      acc[j] = a;
    }
#pragma unroll
    for (int j = 0; j < 4; ++j) {
      const int row = r0 + rowb + j;
      if (row < NTOK) {
        const size_t off = ((size_t)b * NTOK + row) * CDIM + colOut;
        const float t = acc[j] * SP * 64.0f;     // prescaled x64
        const _Float16 h0 = (_Float16)t;
        const float rr = t - (float)h0;
        const _Float16 h1 = (_Float16)(rr * 4096.0f);
        att0[off] = __builtin_bit_cast(unsigned short, h0);
        att1[off] = __builtin_bit_cast(unsigned short, h1);
      }
    }
    __syncthreads();
  }
}

// ---------------------------------------------------------------------------
extern "C" void kernel_launch(void* const* d_in, const int* in_sizes, int n_in,
                              void* d_out, int out_size, void* d_ws, size_t ws_size,
                              hipStream_t stream)
{
  (void)in_sizes; (void)n_in; (void)out_size;
  const float* x      = (const float*)d_in[0];
  const float* qkv_w  = (const float*)d_in[1];
  const float* proj_w = (const float*)d_in[2];
  const float* proj_b = (const float*)d_in[3];
  const float* table  = (const float*)d_in[4];
  const int*   relidx = (const int*)d_in[5];
  float* out = (float*)d_out;

  const size_t biasElems = (size_t)NHEAD * NTOK * NTOK;
  const size_t wqPlane = (size_t)(3 * CDIM) * CDIM;
  const size_t wpPlane = (size_t)CDIM * CDIM;

  // adaptive batch chunk (128-aligned Mpad); 2 limb planes
  int nb = 128;
  size_t Mpad = 0;
  for (;; nb >>= 1) {
    size_t Mreal = (size_t)nb * NTOK;
    Mpad = (Mreal + 127) & ~(size_t)127;
    size_t need = biasElems * 4 + (2 * wqPlane + 2 * wpPlane) * 2 +
                  2 * Mpad * CDIM * 2 +           // x/att split planes (f16)
                  Mreal * (size_t)(3 * CDIM) * 4; // qkv buf (f32)
    if (need <= ws_size || nb == 1) break;
  }

  char* p = (char*)d_ws;
  float* bias_pre = (float*)p;               p += biasElems * 4;
  unsigned short* wq = (unsigned short*)p;   p += 2 * wqPlane * 2;
  unsigned short* wp = (unsigned short*)p;   p += 2 * wpPlane * 2;
  unsigned short* xs = (unsigned short*)p;   p += 2 * Mpad * CDIM * 2;
  float* qkvbuf = (float*)p;

  const size_t xPlane = Mpad * CDIM;

  {
    const int total = (int)biasElems;
    bias_pre_kernel<<<(total + 255) / 256, 256, 0, stream>>>(table, relidx, bias_pre, total);
  }
  {
    long long t4 = (long long)(3 * CDIM) * CDIM / 4;
    split2h_kernel<<<(int)((t4 + 255) / 256), 256, 0, stream>>>(
        qkv_w, wq, wq + wqPlane, 3 * CDIM, CDIM, t4);
    t4 = (long long)CDIM * CDIM / 4;
    split2h_kernel<<<(int)((t4 + 255) / 256), 256, 0, stream>>>(
        proj_w, wp, wp + wpPlane, CDIM, CDIM, t4);
  }

  for (int b0 = 0; b0 < 128; b0 += nb) {
    const int curB = (128 - b0 < nb) ? (128 - b0) : nb;
    const int Mreal = curB * NTOK;
    {
      long long t4 = (long long)Mpad * CDIM / 4;
      split2h_kernel<<<(int)((t4 + 255) / 256), 256, 0, stream>>>(
          x + (size_t)b0 * NTOK * CDIM, xs, xs + xPlane, Mreal, CDIM, t4);
    }
    const int mtiles = (int)(Mpad / 128);
    // qkv: 36 N-tiles of 64, BANDW=18 -> 2 bands
    gemm_f16<18><<<mtiles * 36, 256, 0, stream>>>(
        xs, xPlane, wq, wqPlane, nullptr, qkvbuf, Mreal, 3 * CDIM, CDIM);
    attn_kernel<<<curB * NHEAD, 512, 0, stream>>>(qkvbuf, bias_pre, xs, xs + xPlane);
    // proj: 12 N-tiles of 64, BANDW=12 -> single band
    gemm_f16<12><<<mtiles * 12, 256, 0, stream>>>(
        xs, xPlane, wp, wpPlane, proj_b, out + (size_t)b0 * NTOK * CDIM,
        Mreal, CDIM, CDIM);
  }
}

// Round 19
// 776.170 us; speedup vs baseline: 1.1851x; 1.0298x over previous
//
#include <hip/hip_runtime.h>
#include <cstdint>
#include <cmath>

#define NTOK 197
#define NHEAD 12
#define HD 64
#define CDIM 768
#define KPZ 200
#define VTS 256   // vT row stride (shorts); granule-XOR swizzled

typedef __attribute__((ext_vector_type(8))) short short8v;       // 8 bf16
typedef __attribute__((ext_vector_type(8))) _Float16 half8v;     // 8 fp16
typedef __attribute__((ext_vector_type(4))) float f32x4;

__device__ __forceinline__ unsigned short f2bf(float f) {
  unsigned u = __builtin_bit_cast(unsigned, f);
  unsigned r = (u + 0x7fffu + ((u >> 16) & 1u)) >> 16;   // round-nearest-even
  return (unsigned short)r;
}
__device__ __forceinline__ float bf2f(unsigned short h) {
  unsigned u = ((unsigned)h) << 16;
  return __builtin_bit_cast(float, u);
}

__device__ __forceinline__ void gload_lds16(const unsigned short* g, unsigned short* l) {
  __builtin_amdgcn_global_load_lds(
      (const __attribute__((address_space(1))) unsigned int*)(const void*)g,
      (__attribute__((address_space(3))) unsigned int*)(void*)l, 16, 0, 0);
}

// ---------------------------------------------------------------------------
__global__ __launch_bounds__(256) void bias_pre_kernel(
    const float* __restrict__ table, const int* __restrict__ relidx,
    float* __restrict__ bias_pre, int total)
{
  int i = blockIdx.x * 256 + threadIdx.x;
  if (i >= total) return;
  int nm = i % (NTOK * NTOK);
  int h  = i / (NTOK * NTOK);
  bias_pre[i] = table[relidx[nm] * NHEAD + h];
}

// ---------------------------------------------------------------------------
// Split fp32 [Mreal x C] into 2 scaled-fp16 limb planes [Mpad x C]:
//   t = x*64;  h0 = f16(t);  h1 = f16((t - h0)*4096)
// ---------------------------------------------------------------------------
__global__ __launch_bounds__(256) void split2h_kernel(
    const float* __restrict__ src,
    unsigned short* __restrict__ d0, unsigned short* __restrict__ d1,
    int Mreal, int C, long long total4)
{
  long long idx = (long long)blockIdx.x * 256 + threadIdx.x;
  if (idx >= total4) return;
  long long e = idx * 4;
  int r = (int)(e / C);
  float4 v = make_float4(0.f, 0.f, 0.f, 0.f);
  if (r < Mreal) v = *(const float4*)(src + e);
  const float vv[4] = {v.x, v.y, v.z, v.w};
  ushort4 o0, o1;
  unsigned short* p0 = (unsigned short*)&o0;
  unsigned short* p1 = (unsigned short*)&o1;
#pragma unroll
  for (int i = 0; i < 4; ++i) {
    const float t = vv[i] * 64.0f;
    const _Float16 h0 = (_Float16)t;
    const float rr = t - (float)h0;            // exact (Sterbenz)
    const _Float16 h1 = (_Float16)(rr * 4096.0f);
    p0[i] = __builtin_bit_cast(unsigned short, h0);
    p1[i] = __builtin_bit_cast(unsigned short, h1);
  }
  *(ushort4*)(d0 + e) = o0;
  *(ushort4*)(d1 + e) = o1;
}

// ---------------------------------------------------------------------------
// Scaled-fp16 2-limb MFMA GEMM -- the r16 champion config (777us).
// 128x64 block tile, BK=64, 4 waves (2x2 of 64x32), __launch_bounds__(256,3),
// 3 blocks/CU (unified live set ~148 < 170 cap, no spill). Two-phase K-tile:
// phase0 streams K-half-0 frags; phase1 reads all K-half-1 frags -> barrier
// -> stage(next) -> MFMAs (cover flight) -> barrier. Granule XOR swizzle
// g^(row&7) on pre-swizzled global source, tid-linear LDS dest.
// Per-element MFMA order {00,01,10} per K-32 slice, K ascending --
// bit-identical output (absmax canary 0.0078125).
// ---------------------------------------------------------------------------
template <int BANDW>
__global__ __launch_bounds__(256, 3) void gemm_f16(
    const unsigned short* __restrict__ A, size_t aplane,
    const unsigned short* __restrict__ B, size_t bplane,
    const float* __restrict__ bias, float* __restrict__ C,
    int M, int N, int K)
{
  __shared__ unsigned short Asm[2][128][64];   // 32KB
  __shared__ unsigned short Bsm[2][64][64];    // 16KB

  const int nwg = gridDim.x;
  const int orig = blockIdx.x;
  const int q = nwg >> 3, r = nwg & 7;
  const int xcd = orig & 7, pos = orig >> 3;
  const int wg = (xcd < r ? xcd * (q + 1) : r * (q + 1) + (xcd - r) * q) + pos;
  const int byCount = (M + 127) >> 7;
  const int bandSz = byCount * BANDW;
  const int band = wg / bandSz;
  const int rem = wg % bandSz;
  const int by = rem / BANDW;
  const int bx = band * BANDW + rem % BANDW;
  const int bm = by * 128, bn = bx * 64;

  const int tid = threadIdx.x;
  const int w = tid >> 6, lane = tid & 63;
  const int wr = w >> 1, wc = w & 1;               // 2x2 wave grid
  const int srow = tid >> 3;                       // staging row 0..31 per pass
  const int sslot = tid & 7;                       // granule slot 0..7
  const int sgW = (sslot ^ (srow & 7)) * 8;        // swizzled SOURCE col (shorts)
  const int fr = lane & 15;
  const int fq = lane >> 4;
  const int mrow = wr * 64 + fr;
  const int ncol = wc * 32;
  const int kc0 = 8 * ((fq) ^ (fr & 7));           // K-half 0 read col
  const int kc1 = 8 * ((4 + fq) ^ (fr & 7));       // K-half 1 read col

  size_t aoffs[4], boffs[2];
#pragma unroll
  for (int ps = 0; ps < 4; ++ps) aoffs[ps] = (size_t)(bm + srow + 32 * ps) * K + sgW;
#pragma unroll
  for (int ps = 0; ps < 2; ++ps) boffs[ps] = (size_t)(bn + srow + 32 * ps) * K + sgW;

  f32x4 accA[4][2], accB[4][2];
#pragma unroll
  for (int i = 0; i < 4; ++i)
#pragma unroll
    for (int j = 0; j < 2; ++j) {
      accA[i][j] = (f32x4){0.f, 0.f, 0.f, 0.f};
      accB[i][j] = (f32x4){0.f, 0.f, 0.f, 0.f};
    }

  auto stage = [&](int k0) {
#pragma unroll
    for (int ps = 0; ps < 4; ++ps) {
      const int dr = srow + 32 * ps;
      gload_lds16(A + aoffs[ps] + k0,          &Asm[0][dr][sslot * 8]);
      gload_lds16(A + aplane + aoffs[ps] + k0, &Asm[1][dr][sslot * 8]);
    }
#pragma unroll
    for (int ps = 0; ps < 2; ++ps) {
      const int dr = srow + 32 * ps;
      gload_lds16(B + boffs[ps] + k0,          &Bsm[0][dr][sslot * 8]);
      gload_lds16(B + bplane + boffs[ps] + k0, &Bsm[1][dr][sslot * 8]);
    }
  };

  stage(0);
  __syncthreads();

#pragma unroll 1
  for (int k0 = 0; k0 < K; k0 += 64) {
    // ---- phase 0: K-half 0 (stream A per mt; B cached) ----
    {
      half8v b0[2], b1[2];
#pragma unroll
      for (int nt = 0; nt < 2; ++nt) {
        b0[nt] = *(const half8v*)&Bsm[0][ncol + nt * 16 + fr][kc0];
        b1[nt] = *(const half8v*)&Bsm[1][ncol + nt * 16 + fr][kc0];
      }
#pragma unroll
      for (int mt = 0; mt < 4; ++mt) {
        const half8v a0 = *(const half8v*)&Asm[0][mrow + mt * 16][kc0];
        const half8v a1 = *(const half8v*)&Asm[1][mrow + mt * 16][kc0];
#pragma unroll
        for (int nt = 0; nt < 2; ++nt)
          accA[mt][nt] = __builtin_amdgcn_mfma_f32_16x16x32_f16(
              a0, b0[nt], accA[mt][nt], 0, 0, 0);
#pragma unroll
        for (int nt = 0; nt < 2; ++nt)
          accB[mt][nt] = __builtin_amdgcn_mfma_f32_16x16x32_f16(
              a0, b1[nt], accB[mt][nt], 0, 0, 0);
#pragma unroll
        for (int nt = 0; nt < 2; ++nt)
          accB[mt][nt] = __builtin_amdgcn_mfma_f32_16x16x32_f16(
              a1, b0[nt], accB[mt][nt], 0, 0, 0);
      }
    }
    // ---- phase 1: read ALL K-half-1 frags -> barrier -> stage -> MFMAs ----
    {
      half8v a0[4], a1[4], b0[2], b1[2];
#pragma unroll
      for (int mt = 0; mt < 4; ++mt) {
        a0[mt] = *(const half8v*)&Asm[0][mrow + mt * 16][kc1];
        a1[mt] = *(const half8v*)&Asm[1][mrow + mt * 16][kc1];
      }
#pragma unroll
      for (int nt = 0; nt < 2; ++nt) {
        b0[nt] = *(const half8v*)&Bsm[0][ncol + nt * 16 + fr][kc1];
        b1[nt] = *(const half8v*)&Bsm[1][ncol + nt * 16 + fr][kc1];
      }
      __syncthreads();                 // all reads of this buffer complete
      if (k0 + 64 < K) stage(k0 + 64);
      __builtin_amdgcn_sched_barrier(0);
#pragma unroll
      for (int mt = 0; mt < 4; ++mt)
#pragma unroll
        for (int nt = 0; nt < 2; ++nt)
          accA[mt][nt] = __builtin_amdgcn_mfma_f32_16x16x32_f16(
              a0[mt], b0[nt], accA[mt][nt], 0, 0, 0);
#pragma unroll
      for (int mt = 0; mt < 4; ++mt)
#pragma unroll
        for (int nt = 0; nt < 2; ++nt)
          accB[mt][nt] = __builtin_amdgcn_mfma_f32_16x16x32_f16(
              a0[mt], b1[nt], accB[mt][nt], 0, 0, 0);
#pragma unroll
      for (int mt = 0; mt < 4; ++mt)
#pragma unroll
        for (int nt = 0; nt < 2; ++nt)
          accB[mt][nt] = __builtin_amdgcn_mfma_f32_16x16x32_f16(
              a1[mt], b0[nt], accB[mt][nt], 0, 0, 0);
    }
    __syncthreads();                   // staged loads drained; next tile visible
  }

  // epilogue: C/D layout col = lane&15, row = (lane>>4)*4 + j
  constexpr float S1 = 1.0f / 4096.0f;
#pragma unroll
  for (int nt = 0; nt < 2; ++nt) {
    const int col = bn + wc * 32 + nt * 16 + fr;
    const float bcol = bias ? bias[col] : 0.0f;
#pragma unroll
    for (int mt = 0; mt < 4; ++mt) {
      const int rowbase = bm + wr * 64 + mt * 16 + fq * 4;
#pragma unroll
      for (int j = 0; j < 4; ++j) {
        const int row = rowbase + j;
        if (row < M)
          C[(size_t)row * N + col] =
              (accA[mt][nt][j] + accB[mt][nt][j] * S1) * S1 + bcol;
      }
    }
  }
}

// ---------------------------------------------------------------------------
// Fused binary attention per (b,h), 8 waves, MFMA PV (r16 champion config:
// granule-XOR swizzled vT, u8 zb).
// ---------------------------------------------------------------------------
__global__ __launch_bounds__(512, 4) void attn_kernel(
    const float* __restrict__ qkv, const float* __restrict__ bias_pre,
    unsigned short* __restrict__ att0, unsigned short* __restrict__ att1)
{
  __shared__ unsigned short vT[2][HD][VTS];
  __shared__ unsigned char  zb[32][KPZ];
  __shared__ unsigned long long qb[200];
  __shared__ unsigned long long kbt[200];
  __shared__ float red[16];

  const int bh = blockIdx.x;
  const int b = bh / NHEAD;
  const int h = bh % NHEAD;
  const int tid = threadIdx.x;
  const int w = tid >> 6;
  const int lane = tid & 63;
  const float* base = qkv + (size_t)b * (NTOK * 3 * CDIM) + h * HD;

  float sq = 0.f, sk = 0.f;
  for (int n = w; n < NTOK; n += 8) {
    const float* row = base + (size_t)n * (3 * CDIM);
    const float qv = row[lane];
    const float kv = row[CDIM + lane];
    const float vv = row[2 * CDIM + lane];
    sq += fabsf(qv);
    sk += fabsf(kv);
    const unsigned long long qm = __ballot(qv >= 0.0f);
    const unsigned long long km = __ballot(kv >= 0.0f);
    if (lane == 0) { qb[n] = qm; kbt[n] = km; }
    const float c = fminf(fmaxf(vv, -2.0f), 2.0f);
    float a = fabsf(c);
#pragma unroll
    for (int off = 32; off; off >>= 1) a = fmaxf(a, __shfl_xor(a, off));
    const float s = 127.0f / (a + 1e-8f);
    const float vq = rintf(c * s) / s;
    const unsigned short l0 = f2bf(vq);
    const unsigned short l1 = f2bf(vq - bf2f(l0));
    const int gsw = ((((n >> 3) ^ (lane & 31)) << 3) | (n & 7));
    vT[0][lane][gsw] = l0;
    vT[1][lane][gsw] = l1;
  }
#pragma unroll
  for (int off = 32; off; off >>= 1) {
    sq += __shfl_xor(sq, off);
    sk += __shfl_xor(sk, off);
  }
  if (lane == 0) { red[w] = sq; red[8 + w] = sk; }
  __syncthreads();
  float s_q = 0.f, s_k = 0.f;
#pragma unroll
  for (int i = 0; i < 8; ++i) { s_q += red[i]; s_k += red[8 + i]; }
  s_q *= (1.0f / (NTOK * HD));
  s_k *= (1.0f / (NTOK * HD));
  const float coef = s_q * s_k * 0.125f;

  const float* biash = bias_pre + (size_t)h * (NTOK * NTOK);
  const float SP = 1.0f / 255.0f;

  const int mt = w >> 2;
  const int nt = w & 3;
  const int arow = mt * 16 + (lane & 15);
  const int bcol = nt * 16 + (lane & 15);
  const int kq8 = 8 * (lane >> 4);
  const int rowb = mt * 16 + ((lane >> 4) << 2);
  const int colOut = h * HD + bcol;
  const int bsw = bcol & 31;   // vT read swizzle key

  for (int g = 0; g < 7; ++g) {
    const int r0 = g * 32;

#pragma unroll
    for (int i = 0; i < 4; ++i) {
      const int r = r0 + w * 4 + i;
      if (r < NTOK) {
        const unsigned long long qn = qb[r];
        const float* brow = biash + (size_t)r * NTOK;
        float lg[4];
#pragma unroll
        for (int t = 0; t < 4; ++t) {
          const int m = lane + t * 64;
          if (m < NTOK) {
            const int dot = 64 - 2 * __popcll(qn ^ kbt[m]);
            lg[t] = fmaf(coef, (float)dot, brow[m]);
          } else {
            lg[t] = -INFINITY;
          }
        }
        float mx = fmaxf(fmaxf(lg[0], lg[1]), fmaxf(lg[2], lg[3]));
#pragma unroll
        for (int off = 32; off; off >>= 1) mx = fmaxf(mx, __shfl_xor(mx, off));
        const float p0 = expf(lg[0] - mx);
        const float p1 = expf(lg[1] - mx);
        const float p2 = expf(lg[2] - mx);
        const float p3 = expf(lg[3] - mx);
        float sum = p0 + p1 + p2 + p3;
#pragma unroll
        for (int off = 32; off; off >>= 1) sum += __shfl_xor(sum, off);
        float z0 = rintf((p0 / sum) / SP); z0 = fminf(fmaxf(z0, 0.f), 255.f);
        float z1 = rintf((p1 / sum) / SP); z1 = fminf(fmaxf(z1, 0.f), 255.f);
        float z2 = rintf((p2 / sum) / SP); z2 = fminf(fmaxf(z2, 0.f), 255.f);
        float z3 = rintf((p3 / sum) / SP); z3 = fminf(fmaxf(z3, 0.f), 255.f);
        const int zr = w * 4 + i;
        zb[zr][lane]       = (unsigned char)(int)z0;
        zb[zr][lane + 64]  = (unsigned char)(int)z1;
        zb[zr][lane + 128] = (unsigned char)(int)z2;
        if (lane + 192 < NTOK) zb[zr][lane + 192] = (unsigned char)(int)z3;
      }
    }
    __syncthreads();

    f32x4 acc = (f32x4){0.f, 0.f, 0.f, 0.f};
#pragma unroll
    for (int k0 = 0; k0 < 192; k0 += 32) {
      const unsigned long long a8 =
          *(const unsigned long long*)&zb[arow][k0 + kq8];
      short8v af;
#pragma unroll
      for (int j = 0; j < 8; ++j) {
        const float f = (float)((unsigned)(a8 >> (8 * j)) & 0xFFu);
        af[j] = (short)(__builtin_bit_cast(unsigned, f) >> 16);
      }
      const int kg = (((k0 + kq8) >> 3) ^ bsw) << 3;
      const short8v b0 = *(const short8v*)&vT[0][bcol][kg];
      const short8v b1 = *(const short8v*)&vT[1][bcol][kg];
      acc = __builtin_amdgcn_mfma_f32_16x16x32_bf16(af, b0, acc, 0, 0, 0);
      acc = __builtin_amdgcn_mfma_f32_16x16x32_bf16(af, b1, acc, 0, 0, 0);
    }
#pragma unroll
    for (int j = 0; j < 4; ++j) {
      float a = acc[j];
#pragma unroll
      for (int m = 192; m < 197; ++m) {
        const int mg = ((((m >> 3) ^ bsw) << 3) | (m & 7));
        const float zv = (float)zb[rowb + j][m];
        const float vv = bf2f(vT[0][bcol][mg]) + bf2f(vT[1][bcol][mg]);
        a = fmaf(zv, vv, a);
      }
      acc[j] = a;
    }
#pragma unroll
    for (int j = 0; j < 4; ++j) {
      const int row = r0 + rowb + j;
      if (row < NTOK) {
        const size_t off = ((size_t)b * NTOK + row) * CDIM + colOut;
        const float t = acc[j] * SP * 64.0f;     // prescaled x64
        const _Float16 h0 = (_Float16)t;
        const float rr = t - (float)h0;
        const _Float16 h1 = (_Float16)(rr * 4096.0f);
        att0[off] = __builtin_bit_cast(unsigned short, h0);
        att1[off] = __builtin_bit_cast(unsigned short, h1);
      }
    }
    __syncthreads();
  }
}

// ---------------------------------------------------------------------------
extern "C" void kernel_launch(void* const* d_in, const int* in_sizes, int n_in,
                              void* d_out, int out_size, void* d_ws, size_t ws_size,
                              hipStream_t stream)
{
  (void)in_sizes; (void)n_in; (void)out_size;
  const float* x      = (const float*)d_in[0];
  const float* qkv_w  = (const float*)d_in[1];
  const float* proj_w = (const float*)d_in[2];
  const float* proj_b = (const float*)d_in[3];
  const float* table  = (const float*)d_in[4];
  const int*   relidx = (const int*)d_in[5];
  float* out = (float*)d_out;

  const size_t biasElems = (size_t)NHEAD * NTOK * NTOK;
  const size_t wqPlane = (size_t)(3 * CDIM) * CDIM;
  const size_t wpPlane = (size_t)CDIM * CDIM;

  // adaptive batch chunk (128-aligned Mpad); 2 limb planes
  int nb = 128;
  size_t Mpad = 0;
  for (;; nb >>= 1) {
    size_t Mreal = (size_t)nb * NTOK;
    Mpad = (Mreal + 127) & ~(size_t)127;
    size_t need = biasElems * 4 + (2 * wqPlane + 2 * wpPlane) * 2 +
                  2 * Mpad * CDIM * 2 +           // x/att split planes (f16)
                  Mreal * (size_t)(3 * CDIM) * 4; // qkv buf (f32)
    if (need <= ws_size || nb == 1) break;
  }

  char* p = (char*)d_ws;
  float* bias_pre = (float*)p;               p += biasElems * 4;
  unsigned short* wq = (unsigned short*)p;   p += 2 * wqPlane * 2;
  unsigned short* wp = (unsigned short*)p;   p += 2 * wpPlane * 2;
  unsigned short* xs = (unsigned short*)p;   p += 2 * Mpad * CDIM * 2;
  float* qkvbuf = (float*)p;

  const size_t xPlane = Mpad * CDIM;

  {
    const int total = (int)biasElems;
    bias_pre_kernel<<<(total + 255) / 256, 256, 0, stream>>>(table, relidx, bias_pre, total);
  }
  {
    long long t4 = (long long)(3 * CDIM) * CDIM / 4;
    split2h_kernel<<<(int)((t4 + 255) / 256), 256, 0, stream>>>(
        qkv_w, wq, wq + wqPlane, 3 * CDIM, CDIM, t4);
    t4 = (long long)CDIM * CDIM / 4;
    split2h_kernel<<<(int)((t4 + 255) / 256), 256, 0, stream>>>(
        proj_w, wp, wp + wpPlane, CDIM, CDIM, t4);
  }

  for (int b0 = 0; b0 < 128; b0 += nb) {
    const int curB = (128 - b0 < nb) ? (128 - b0) : nb;
    const int Mreal = curB * NTOK;
    {
      long long t4 = (long long)Mpad * CDIM / 4;
      split2h_kernel<<<(int)((t4 + 255) / 256), 256, 0, stream>>>(
          x + (size_t)b0 * NTOK * CDIM, xs, xs + xPlane, Mreal, CDIM, t4);
    }
    const int mtiles = (int)(Mpad / 128);
    // qkv: 36 N-tiles of 64, BANDW=18 -> 2 bands
    gemm_f16<18><<<mtiles * 36, 256, 0, stream>>>(
        xs, xPlane, wq, wqPlane, nullptr, qkvbuf, Mreal, 3 * CDIM, CDIM);
    attn_kernel<<<curB * NHEAD, 512, 0, stream>>>(qkvbuf, bias_pre, xs, xs + xPlane);
    // proj: 12 N-tiles of 64, BANDW=12 -> single band
    gemm_f16<12><<<mtiles * 12, 256, 0, stream>>>(
        xs, xPlane, wp, wpPlane, proj_b, out + (size_t)b0 * NTOK * CDIM,
        Mreal, CDIM, CDIM);
  }
}

// Round 20
// 752.870 us; speedup vs baseline: 1.2218x; 1.0309x over previous
//
#include <hip/hip_runtime.h>
#include <cstdint>
#include <cmath>

#define NTOK 197
#define NHEAD 12
#define HD 64
#define CDIM 768
#define KPZ 200
#define VTS 256   // vT row stride (shorts); granule-XOR swizzled

typedef __attribute__((ext_vector_type(8))) short short8v;       // 8 bf16
typedef __attribute__((ext_vector_type(8))) _Float16 half8v;     // 8 fp16
typedef __attribute__((ext_vector_type(4))) float f32x4;

__device__ __forceinline__ unsigned short f2bf(float f) {
  unsigned u = __builtin_bit_cast(unsigned, f);
  unsigned r = (u + 0x7fffu + ((u >> 16) & 1u)) >> 16;   // round-nearest-even
  return (unsigned short)r;
}
__device__ __forceinline__ float bf2f(unsigned short h) {
  unsigned u = ((unsigned)h) << 16;
  return __builtin_bit_cast(float, u);
}

__device__ __forceinline__ void gload_lds16(const unsigned short* g, unsigned short* l) {
  __builtin_amdgcn_global_load_lds(
      (const __attribute__((address_space(1))) unsigned int*)(const void*)g,
      (__attribute__((address_space(3))) unsigned int*)(void*)l, 16, 0, 0);
}

// ---------------------------------------------------------------------------
__global__ __launch_bounds__(256) void bias_pre_kernel(
    const float* __restrict__ table, const int* __restrict__ relidx,
    float* __restrict__ bias_pre, int total)
{
  int i = blockIdx.x * 256 + threadIdx.x;
  if (i >= total) return;
  int nm = i % (NTOK * NTOK);
  int h  = i / (NTOK * NTOK);
  bias_pre[i] = table[relidx[nm] * NHEAD + h];
}

// ---------------------------------------------------------------------------
// Split fp32 [Mreal x C] into 2 scaled-fp16 limb planes [Mpad x C]:
//   t = x*64;  h0 = f16(t);  h1 = f16((t - h0)*4096)
// ---------------------------------------------------------------------------
__global__ __launch_bounds__(256) void split2h_kernel(
    const float* __restrict__ src,
    unsigned short* __restrict__ d0, unsigned short* __restrict__ d1,
    int Mreal, int C, long long total4)
{
  long long idx = (long long)blockIdx.x * 256 + threadIdx.x;
  if (idx >= total4) return;
  long long e = idx * 4;
  int r = (int)(e / C);
  float4 v = make_float4(0.f, 0.f, 0.f, 0.f);
  if (r < Mreal) v = *(const float4*)(src + e);
  const float vv[4] = {v.x, v.y, v.z, v.w};
  ushort4 o0, o1;
  unsigned short* p0 = (unsigned short*)&o0;
  unsigned short* p1 = (unsigned short*)&o1;
#pragma unroll
  for (int i = 0; i < 4; ++i) {
    const float t = vv[i] * 64.0f;
    const _Float16 h0 = (_Float16)t;
    const float rr = t - (float)h0;            // exact (Sterbenz)
    const _Float16 h1 = (_Float16)(rr * 4096.0f);
    p0[i] = __builtin_bit_cast(unsigned short, h0);
    p1[i] = __builtin_bit_cast(unsigned short, h1);
  }
  *(ushort4*)(d0 + e) = o0;
  *(ushort4*)(d1 + e) = o1;
}

// ---------------------------------------------------------------------------
// Scaled-fp16 2-limb MFMA GEMM -- r16 champion loop (777us) + LDS-bounce
// epilogue. 128x64 block tile, BK=64, 4 waves (2x2 of 64x32),
// __launch_bounds__(256,3), 3 blocks/CU. Two-phase K-tile: phase0 streams
// K-half-0 frags; phase1 reads all K-half-1 frags -> barrier -> stage(next)
// -> MFMAs (cover flight) -> barrier.
// EPILOGUE (new): C-tile bounced through LDS (overlaid on dead Asm, stride
// 68 dwords = 16B-aligned rows, 2-way banks) then streamed out as float4,
// 256B contiguous per wave = full 128B lines -> kills the ~116MB/dispatch
// read-for-ownership traffic the scalar stores caused. Values per output
// element identical ((accA+accB*S1)*S1 + bias) -> bit-identical output
// (absmax canary 0.0078125).
// ---------------------------------------------------------------------------
template <int BANDW>
__global__ __launch_bounds__(256, 3) void gemm_f16(
    const unsigned short* __restrict__ A, size_t aplane,
    const unsigned short* __restrict__ B, size_t bplane,
    const float* __restrict__ bias, float* __restrict__ C,
    int M, int N, int K)
{
  __shared__ unsigned short Asm[2][128][64];   // 32KB (epilogue reuses as f32 stage)
  __shared__ unsigned short Bsm[2][64][64];    // 16KB

  const int nwg = gridDim.x;
  const int orig = blockIdx.x;
  const int q = nwg >> 3, r = nwg & 7;
  const int xcd = orig & 7, pos = orig >> 3;
  const int wg = (xcd < r ? xcd * (q + 1) : r * (q + 1) + (xcd - r) * q) + pos;
  const int byCount = (M + 127) >> 7;
  const int bandSz = byCount * BANDW;
  const int band = wg / bandSz;
  const int rem = wg % bandSz;
  const int by = rem / BANDW;
  const int bx = band * BANDW + rem % BANDW;
  const int bm = by * 128, bn = bx * 64;

  const int tid = threadIdx.x;
  const int w = tid >> 6, lane = tid & 63;
  const int wr = w >> 1, wc = w & 1;               // 2x2 wave grid
  const int srow = tid >> 3;                       // staging row 0..31 per pass
  const int sslot = tid & 7;                       // granule slot 0..7
  const int sgW = (sslot ^ (srow & 7)) * 8;        // swizzled SOURCE col (shorts)
  const int fr = lane & 15;
  const int fq = lane >> 4;
  const int mrow = wr * 64 + fr;
  const int ncol = wc * 32;
  const int kc0 = 8 * ((fq) ^ (fr & 7));           // K-half 0 read col
  const int kc1 = 8 * ((4 + fq) ^ (fr & 7));       // K-half 1 read col

  size_t aoffs[4], boffs[2];
#pragma unroll
  for (int ps = 0; ps < 4; ++ps) aoffs[ps] = (size_t)(bm + srow + 32 * ps) * K + sgW;
#pragma unroll
  for (int ps = 0; ps < 2; ++ps) boffs[ps] = (size_t)(bn + srow + 32 * ps) * K + sgW;

  f32x4 accA[4][2], accB[4][2];
#pragma unroll
  for (int i = 0; i < 4; ++i)
#pragma unroll
    for (int j = 0; j < 2; ++j) {
      accA[i][j] = (f32x4){0.f, 0.f, 0.f, 0.f};
      accB[i][j] = (f32x4){0.f, 0.f, 0.f, 0.f};
    }

  auto stage = [&](int k0) {
#pragma unroll
    for (int ps = 0; ps < 4; ++ps) {
      const int dr = srow + 32 * ps;
      gload_lds16(A + aoffs[ps] + k0,          &Asm[0][dr][sslot * 8]);
      gload_lds16(A + aplane + aoffs[ps] + k0, &Asm[1][dr][sslot * 8]);
    }
#pragma unroll
    for (int ps = 0; ps < 2; ++ps) {
      const int dr = srow + 32 * ps;
      gload_lds16(B + boffs[ps] + k0,          &Bsm[0][dr][sslot * 8]);
      gload_lds16(B + bplane + boffs[ps] + k0, &Bsm[1][dr][sslot * 8]);
    }
  };

  stage(0);
  __syncthreads();

#pragma unroll 1
  for (int k0 = 0; k0 < K; k0 += 64) {
    // ---- phase 0: K-half 0 (stream A per mt; B cached) ----
    {
      half8v b0[2], b1[2];
#pragma unroll
      for (int nt = 0; nt < 2; ++nt) {
        b0[nt] = *(const half8v*)&Bsm[0][ncol + nt * 16 + fr][kc0];
        b1[nt] = *(const half8v*)&Bsm[1][ncol + nt * 16 + fr][kc0];
      }
#pragma unroll
      for (int mt = 0; mt < 4; ++mt) {
        const half8v a0 = *(const half8v*)&Asm[0][mrow + mt * 16][kc0];
        const half8v a1 = *(const half8v*)&Asm[1][mrow + mt * 16][kc0];
#pragma unroll
        for (int nt = 0; nt < 2; ++nt)
          accA[mt][nt] = __builtin_amdgcn_mfma_f32_16x16x32_f16(
              a0, b0[nt], accA[mt][nt], 0, 0, 0);
#pragma unroll
        for (int nt = 0; nt < 2; ++nt)
          accB[mt][nt] = __builtin_amdgcn_mfma_f32_16x16x32_f16(
              a0, b1[nt], accB[mt][nt], 0, 0, 0);
#pragma unroll
        for (int nt = 0; nt < 2; ++nt)
          accB[mt][nt] = __builtin_amdgcn_mfma_f32_16x16x32_f16(
              a1, b0[nt], accB[mt][nt], 0, 0, 0);
      }
    }
    // ---- phase 1: read ALL K-half-1 frags -> barrier -> stage -> MFMAs ----
    {
      half8v a0[4], a1[4], b0[2], b1[2];
#pragma unroll
      for (int mt = 0; mt < 4; ++mt) {
        a0[mt] = *(const half8v*)&Asm[0][mrow + mt * 16][kc1];
        a1[mt] = *(const half8v*)&Asm[1][mrow + mt * 16][kc1];
      }
#pragma unroll
      for (int nt = 0; nt < 2; ++nt) {
        b0[nt] = *(const half8v*)&Bsm[0][ncol + nt * 16 + fr][kc1];
        b1[nt] = *(const half8v*)&Bsm[1][ncol + nt * 16 + fr][kc1];
      }
      __syncthreads();                 // all reads of this buffer complete
      if (k0 + 64 < K) stage(k0 + 64);
      __builtin_amdgcn_sched_barrier(0);
#pragma unroll
      for (int mt = 0; mt < 4; ++mt)
#pragma unroll
        for (int nt = 0; nt < 2; ++nt)
          accA[mt][nt] = __builtin_amdgcn_mfma_f32_16x16x32_f16(
              a0[mt], b0[nt], accA[mt][nt], 0, 0, 0);
#pragma unroll
      for (int mt = 0; mt < 4; ++mt)
#pragma unroll
        for (int nt = 0; nt < 2; ++nt)
          accB[mt][nt] = __builtin_amdgcn_mfma_f32_16x16x32_f16(
              a0[mt], b1[nt], accB[mt][nt], 0, 0, 0);
#pragma unroll
      for (int mt = 0; mt < 4; ++mt)
#pragma unroll
        for (int nt = 0; nt < 2; ++nt)
          accB[mt][nt] = __builtin_amdgcn_mfma_f32_16x16x32_f16(
              a1[mt], b0[nt], accB[mt][nt], 0, 0, 0);
    }
    __syncthreads();                   // staged loads drained; next tile visible
  }

  // ---- LDS-bounce epilogue: full-line coalesced C stores (no RFO) ----
  // cstage overlays dead Asm: 64 rows x 68 dwords (16B-aligned, 2-way banks).
  constexpr float S1 = 1.0f / 4096.0f;
  float* cstage = (float*)&Asm[0][0][0];   // 64*68*4 = 17,408 B <= 32KB
#pragma unroll 1
  for (int h2 = 0; h2 < 2; ++h2) {
    if (wr == h2) {
#pragma unroll
      for (int nt = 0; nt < 2; ++nt) {
        const int ccol = wc * 32 + nt * 16 + fr;
        const float bcol = bias ? bias[bn + ccol] : 0.0f;
#pragma unroll
        for (int mt = 0; mt < 4; ++mt) {
#pragma unroll
          for (int j = 0; j < 4; ++j) {
            cstage[(mt * 16 + fq * 4 + j) * 68 + ccol] =
                (accA[mt][nt][j] + accB[mt][nt][j] * S1) * S1 + bcol;
          }
        }
      }
    }
    __syncthreads();
#pragma unroll
    for (int pp = 0; pp < 4; ++pp) {
      const int rloc = pp * 16 + (tid >> 4);
      const int c4 = (tid & 15) * 4;
      const int grow = bm + h2 * 64 + rloc;
      if (grow < M) {
        const float4 v = *(const float4*)&cstage[rloc * 68 + c4];
        *(float4*)(C + (size_t)grow * N + bn + c4) = v;
      }
    }
    __syncthreads();
  }
}

// ---------------------------------------------------------------------------
// Fused binary attention per (b,h), 8 waves, MFMA PV (r16 champion config:
// granule-XOR swizzled vT, u8 zb).
// ---------------------------------------------------------------------------
__global__ __launch_bounds__(512, 4) void attn_kernel(
    const float* __restrict__ qkv, const float* __restrict__ bias_pre,
    unsigned short* __restrict__ att0, unsigned short* __restrict__ att1)
{
  __shared__ unsigned short vT[2][HD][VTS];
  __shared__ unsigned char  zb[32][KPZ];
  __shared__ unsigned long long qb[200];
  __shared__ unsigned long long kbt[200];
  __shared__ float red[16];

  const int bh = blockIdx.x;
  const int b = bh / NHEAD;
  const int h = bh % NHEAD;
  const int tid = threadIdx.x;
  const int w = tid >> 6;
  const int lane = tid & 63;
  const float* base = qkv + (size_t)b * (NTOK * 3 * CDIM) + h * HD;

  float sq = 0.f, sk = 0.f;
  for (int n = w; n < NTOK; n += 8) {
    const float* row = base + (size_t)n * (3 * CDIM);
    const float qv = row[lane];
    const float kv = row[CDIM + lane];
    const float vv = row[2 * CDIM + lane];
    sq += fabsf(qv);
    sk += fabsf(kv);
    const unsigned long long qm = __ballot(qv >= 0.0f);
    const unsigned long long km = __ballot(kv >= 0.0f);
    if (lane == 0) { qb[n] = qm; kbt[n] = km; }
    const float c = fminf(fmaxf(vv, -2.0f), 2.0f);
    float a = fabsf(c);
#pragma unroll
    for (int off = 32; off; off >>= 1) a = fmaxf(a, __shfl_xor(a, off));
    const float s = 127.0f / (a + 1e-8f);
    const float vq = rintf(c * s) / s;
    const unsigned short l0 = f2bf(vq);
    const unsigned short l1 = f2bf(vq - bf2f(l0));
    const int gsw = ((((n >> 3) ^ (lane & 31)) << 3) | (n & 7));
    vT[0][lane][gsw] = l0;
    vT[1][lane][gsw] = l1;
  }
#pragma unroll
  for (int off = 32; off; off >>= 1) {
    sq += __shfl_xor(sq, off);
    sk += __shfl_xor(sk, off);
  }
  if (lane == 0) { red[w] = sq; red[8 + w] = sk; }
  __syncthreads();
  float s_q = 0.f, s_k = 0.f;
#pragma unroll
  for (int i = 0; i < 8; ++i) { s_q += red[i]; s_k += red[8 + i]; }
  s_q *= (1.0f / (NTOK * HD));
  s_k *= (1.0f / (NTOK * HD));
  const float coef = s_q * s_k * 0.125f;

  const float* biash = bias_pre + (size_t)h * (NTOK * NTOK);
  const float SP = 1.0f / 255.0f;

  const int mt = w >> 2;
  const int nt = w & 3;
  const int arow = mt * 16 + (lane & 15);
  const int bcol = nt * 16 + (lane & 15);
  const int kq8 = 8 * (lane >> 4);
  const int rowb = mt * 16 + ((lane >> 4) << 2);
  const int colOut = h * HD + bcol;
  const int bsw = bcol & 31;   // vT read swizzle key

  for (int g = 0; g < 7; ++g) {
    const int r0 = g * 32;

#pragma unroll
    for (int i = 0; i < 4; ++i) {
      const int r = r0 + w * 4 + i;
      if (r < NTOK) {
        const unsigned long long qn = qb[r];
        const float* brow = biash + (size_t)r * NTOK;
        float lg[4];
#pragma unroll
        for (int t = 0; t < 4; ++t) {
          const int m = lane + t * 64;
          if (m < NTOK) {
            const int dot = 64 - 2 * __popcll(qn ^ kbt[m]);
            lg[t] = fmaf(coef, (float)dot, brow[m]);
          } else {
            lg[t] = -INFINITY;
          }
        }
        float mx = fmaxf(fmaxf(lg[0], lg[1]), fmaxf(lg[2], lg[3]));
#pragma unroll
        for (int off = 32; off; off >>= 1) mx = fmaxf(mx, __shfl_xor(mx, off));
        const float p0 = expf(lg[0] - mx);
        const float p1 = expf(lg[1] - mx);
        const float p2 = expf(lg[2] - mx);
        const float p3 = expf(lg[3] - mx);
        float sum = p0 + p1 + p2 + p3;
#pragma unroll
        for (int off = 32; off; off >>= 1) sum += __shfl_xor(sum, off);
        float z0 = rintf((p0 / sum) / SP); z0 = fminf(fmaxf(z0, 0.f), 255.f);
        float z1 = rintf((p1 / sum) / SP); z1 = fminf(fmaxf(z1, 0.f), 255.f);
        float z2 = rintf((p2 / sum) / SP); z2 = fminf(fmaxf(z2, 0.f), 255.f);
        float z3 = rintf((p3 / sum) / SP); z3 = fminf(fmaxf(z3, 0.f), 255.f);
        const int zr = w * 4 + i;
        zb[zr][lane]       = (unsigned char)(int)z0;
        zb[zr][lane + 64]  = (unsigned char)(int)z1;
        zb[zr][lane + 128] = (unsigned char)(int)z2;
        if (lane + 192 < NTOK) zb[zr][lane + 192] = (unsigned char)(int)z3;
      }
    }
    __syncthreads();

    f32x4 acc = (f32x4){0.f, 0.f, 0.f, 0.f};
#pragma unroll
    for (int k0 = 0; k0 < 192; k0 += 32) {
      const unsigned long long a8 =
          *(const unsigned long long*)&zb[arow][k0 + kq8];
      short8v af;
#pragma unroll
      for (int j = 0; j < 8; ++j) {
        const float f = (float)((unsigned)(a8 >> (8 * j)) & 0xFFu);
        af[j] = (short)(__builtin_bit_cast(unsigned, f) >> 16);
      }
      const int kg = (((k0 + kq8) >> 3) ^ bsw) << 3;
      const short8v b0 = *(const short8v*)&vT[0][bcol][kg];
      const short8v b1 = *(const short8v*)&vT[1][bcol][kg];
      acc = __builtin_amdgcn_mfma_f32_16x16x32_bf16(af, b0, acc, 0, 0, 0);
      acc = __builtin_amdgcn_mfma_f32_16x16x32_bf16(af, b1, acc, 0, 0, 0);
    }
#pragma unroll
    for (int j = 0; j < 4; ++j) {
      float a = acc[j];
#pragma unroll
      for (int m = 192; m < 197; ++m) {
        const int mg = ((((m >> 3) ^ bsw) << 3) | (m & 7));
        const float zv = (float)zb[rowb + j][m];
        const float vv = bf2f(vT[0][bcol][mg]) + bf2f(vT[1][bcol][mg]);
        a = fmaf(zv, vv, a);
      }
      acc[j] = a;
    }
#pragma unroll
    for (int j = 0; j < 4; ++j) {
      const int row = r0 + rowb + j;
      if (row < NTOK) {
        const size_t off = ((size_t)b * NTOK + row) * CDIM + colOut;
        const float t = acc[j] * SP * 64.0f;     // prescaled x64
        const _Float16 h0 = (_Float16)t;
        const float rr = t - (float)h0;
        const _Float16 h1 = (_Float16)(rr * 4096.0f);
        att0[off] = __builtin_bit_cast(unsigned short, h0);
        att1[off] = __builtin_bit_cast(unsigned short, h1);
      }
    }
    __syncthreads();
  }
}

// ---------------------------------------------------------------------------
extern "C" void kernel_launch(void* const* d_in, const int* in_sizes, int n_in,
                              void* d_out, int out_size, void* d_ws, size_t ws_size,
                              hipStream_t stream)
{
  (void)in_sizes; (void)n_in; (void)out_size;
  const float* x      = (const float*)d_in[0];
  const float* qkv_w  = (const float*)d_in[1];
  const float* proj_w = (const float*)d_in[2];
  const float* proj_b = (const float*)d_in[3];
  const float* table  = (const float*)d_in[4];
  const int*   relidx = (const int*)d_in[5];
  float* out = (float*)d_out;

  const size_t biasElems = (size_t)NHEAD * NTOK * NTOK;
  const size_t wqPlane = (size_t)(3 * CDIM) * CDIM;
  const size_t wpPlane = (size_t)CDIM * CDIM;

  // adaptive batch chunk (128-aligned Mpad); 2 limb planes
  int nb = 128;
  size_t Mpad = 0;
  for (;; nb >>= 1) {
    size_t Mreal = (size_t)nb * NTOK;
    Mpad = (Mreal + 127) & ~(size_t)127;
    size_t need = biasElems * 4 + (2 * wqPlane + 2 * wpPlane) * 2 +
                  2 * Mpad * CDIM * 2 +           // x/att split planes (f16)
                  Mreal * (size_t)(3 * CDIM) * 4; // qkv buf (f32)
    if (need <= ws_size || nb == 1) break;
  }

  char* p = (char*)d_ws;
  float* bias_pre = (float*)p;               p += biasElems * 4;
  unsigned short* wq = (unsigned short*)p;   p += 2 * wqPlane * 2;
  unsigned short* wp = (unsigned short*)p;   p += 2 * wpPlane * 2;
  unsigned short* xs = (unsigned short*)p;   p += 2 * Mpad * CDIM * 2;
  float* qkvbuf = (float*)p;

  const size_t xPlane = Mpad * CDIM;

  {
    const int total = (int)biasElems;
    bias_pre_kernel<<<(total + 255) / 256, 256, 0, stream>>>(table, relidx, bias_pre, total);
  }
  {
    long long t4 = (long long)(3 * CDIM) * CDIM / 4;
    split2h_kernel<<<(int)((t4 + 255) / 256), 256, 0, stream>>>(
        qkv_w, wq, wq + wqPlane, 3 * CDIM, CDIM, t4);
    t4 = (long long)CDIM * CDIM / 4;
    split2h_kernel<<<(int)((t4 + 255) / 256), 256, 0, stream>>>(
        proj_w, wp, wp + wpPlane, CDIM, CDIM, t4);
  }

  for (int b0 = 0; b0 < 128; b0 += nb) {
    const int curB = (128 - b0 < nb) ? (128 - b0) : nb;
    const int Mreal = curB * NTOK;
    {
      long long t4 = (long long)Mpad * CDIM / 4;
      split2h_kernel<<<(int)((t4 + 255) / 256), 256, 0, stream>>>(
          x + (size_t)b0 * NTOK * CDIM, xs, xs + xPlane, Mreal, CDIM, t4);
    }
    const int mtiles = (int)(Mpad / 128);
    // qkv: 36 N-tiles of 64, BANDW=18 -> 2 bands
    gemm_f16<18><<<mtiles * 36, 256, 0, stream>>>(
        xs, xPlane, wq, wqPlane, nullptr, qkvbuf, Mreal, 3 * CDIM, CDIM);
    attn_kernel<<<curB * NHEAD, 512, 0, stream>>>(qkvbuf, bias_pre, xs, xs + xPlane);
    // proj: 12 N-tiles of 64, BANDW=12 -> single band
    gemm_f16<12><<<mtiles * 12, 256, 0, stream>>>(
        xs, xPlane, wp, wpPlane, proj_b, out + (size_t)b0 * NTOK * CDIM,
        Mreal, CDIM, CDIM);
  }
}